// Round 2
// baseline (517.649 us; speedup 1.0000x reference)
//
#include <hip/hip_runtime.h>

#define SQ 2048
#define DH 64
#define NH 12
#define NBH 48          // B*H
#define QTILE 128       // q rows per block (32 per wave)
#define KTILE 64        // keys per iteration
#define NITER (SQ / KTILE)
#define NQT (SQ / QTILE)   // 16 q-tiles -> 768 blocks = 3 blocks/CU

typedef short short8 __attribute__((ext_vector_type(8)));
typedef float f32x2  __attribute__((ext_vector_type(2)));
typedef float f32x4  __attribute__((ext_vector_type(4)));
typedef float f32x16 __attribute__((ext_vector_type(16)));
typedef int   i32x2 __attribute__((ext_vector_type(2)));
typedef int   i32x4 __attribute__((ext_vector_type(4)));

#define MFMA32(a, b, c) __builtin_amdgcn_mfma_f32_32x32x16_bf16(a, b, c, 0, 0, 0)

typedef __attribute__((address_space(1))) const void* gas_ptr;
typedef __attribute__((address_space(3))) void* las_ptr;

__device__ __forceinline__ void load_lds16(const void* g, void* l) {
    // 16B/lane direct global->LDS DMA; LDS dest = wave-uniform base + lane*16
    __builtin_amdgcn_global_load_lds((gas_ptr)g, (las_ptr)l, 16, 0, 0);
}

// two fp32 -> packed bf16x2 (low = a, high = b), RTNE
#if defined(__has_builtin) && __has_builtin(__builtin_amdgcn_cvt_pk_bf16_f32)
typedef __bf16 bf16x2_t __attribute__((ext_vector_type(2)));
__device__ __forceinline__ unsigned pk2bf(float a, float b) {
    bf16x2_t v = __builtin_amdgcn_cvt_pk_bf16_f32(a, b);
    union { bf16x2_t v; unsigned u; } c; c.v = v; return c.u;
}
#else
__device__ __forceinline__ unsigned pk2bf(float a, float b) {
    union { float f; unsigned u; } x, y; x.f = a; y.f = b;
    unsigned ra = x.u + 0x7FFFu + ((x.u >> 16) & 1u);
    unsigned rb = y.u + 0x7FFFu + ((y.u >> 16) & 1u);
    return (ra >> 16) | (rb & 0xFFFF0000u);
}
#endif

#ifdef __has_builtin
#if __has_builtin(__builtin_amdgcn_permlane32_swap)
#define HAVE_PLSWAP 1
#else
#define HAVE_PLSWAP 0
#endif
#else
#define HAVE_PLSWAP 0
#endif

// ------- fused pre-pass: K fp32->bf16 (blocks 0..3071)  |  V transpose (rest) -------
#define KCONV_BLOCKS (NBH * SQ * DH / 8 / 256)   // 3072
__global__ __launch_bounds__(256)
void prepass(const float* __restrict__ K, short* __restrict__ Kb,
             const float* __restrict__ V, short* __restrict__ Vt) {
    __shared__ float Ls[64][68];   // transpose staging (+4 pad)
    if (blockIdx.x < KCONV_BLOCKS) {
        const size_t i = (size_t)(blockIdx.x * 256 + threadIdx.x) * 8;
        f32x4 a = *(const f32x4*)&K[i];
        f32x4 b = *(const f32x4*)&K[i + 4];
        unsigned o[4] = { pk2bf(a[0], a[1]), pk2bf(a[2], a[3]),
                          pk2bf(b[0], b[1]), pk2bf(b[2], b[3]) };
        *(i32x4*)&Kb[i] = *(i32x4*)o;
        return;
    }
    const int bx = blockIdx.x - KCONV_BLOCKS;
    const int st = bx & 31;       // s tile
    const int bh = bx >> 5;
    const int b = bh / NH, h = bh % NH;
    const int s0 = st * 64;
    const float* src = V + ((size_t)b * SQ * NH + (size_t)h) * DH;
    const int dg = threadIdx.x & 15;   // d = 4*dg
    const int sl = threadIdx.x >> 4;   // 0..15
    #pragma unroll
    for (int p = 0; p < 4; ++p) {
        const int row = p * 16 + sl;
        *(f32x4*)&Ls[row][dg * 4] =
            *(const f32x4*)&src[(size_t)(s0 + row) * (NH * DH) + dg * 4];
    }
    __syncthreads();
    const int dr = threadIdx.x >> 2;        // d row 0..63
    const int sc = (threadIdx.x & 3) * 16;  // s chunk
    unsigned out[8];
    #pragma unroll
    for (int jj = 0; jj < 8; ++jj)
        out[jj] = pk2bf(Ls[sc + 2 * jj][dr], Ls[sc + 2 * jj + 1][dr]);
    short* dst = Vt + (size_t)bh * DH * SQ + (size_t)dr * SQ + s0 + sc;
    *(i32x4*)(dst)     = *(i32x4*)&out[0];
    *(i32x4*)(dst + 8) = *(i32x4*)&out[4];
}

// ---------------- main fused attention (32x32x16 MFMA, QK-ahead pipeline) ----------------
// Per tile t: {sync; DMA K(t+2),V(t+1); QK(t+1)->s_next [MFMA]; SM(s_cur) [VALU]; PV(t) [MFMA]}
// SM/PV consume the PREVIOUS tile's scores -> no dependence on this tile's QK, so the
// compiler/HW overlap exp2+pack VALU with QK's lgkm waits and matrix-pipe execution.
__global__ __launch_bounds__(256, 3)
void attn_fused_kernel(const float* __restrict__ Q,
                       const short* __restrict__ Kb,   // bf16 [BH][S][D]
                       const short* __restrict__ Vtg,  // bf16 [BH][D][S]
                       float* __restrict__ O) {
    // Flat LDS arena, compile-time offsets after unroll-2:
    //   Kbuf[i] at i*8192   (halves +0 rows0-31, +4096 rows32-63)
    //   Vbuf[i] at 16384 + i*8192 (halves +0 d0-31, +4096 d32-63)
    // XOR chunk swizzle (chunk c of row r at c^(r&7)); unpadded 128B rows.
    __shared__ __align__(16) char L[32768];

    const int tid  = threadIdx.x;
    const int lane = tid & 63;
    const int w    = tid >> 6;
    const int m31  = lane & 31;     // MFMA row/col index
    const int hl   = lane >> 5;     // half-wave 0/1
    const int l7   = lane & 7;

    // ---- XCD-locality swizzle: dispatch round-robins XCDs by (bx & 7).
    const int bx  = blockIdx.x;
    const int xcd = bx & 7;
    const int i96 = bx >> 3;          // 0..95
    const int bh  = xcd * 6 + (i96 % 6);
    const int qt  = i96 / 6;          // 0..15
    const int q0 = qt * QTILE;

    const float* Qb  = Q   + (size_t)bh * SQ * DH;
    const short* Kbh = Kb  + (size_t)bh * SQ * DH;
    const short* Vbh = Vtg + (size_t)bh * DH * SQ;
    float*       Ob  = O   + (size_t)bh * SQ * DH;

    // scale folded into Q, exp as exp2: 1/sqrt(768) * log2(e)
    const float qscale = 0.03608439182435161f * 1.4426950408889634f;

    // ---- Q fragments (B operand: n=m31 -> q row, k=16*s+8*hl+j) ----
    short8 qf[4];
    {
        const int qrow = q0 + 32 * w + m31;
        #pragma unroll
        for (int s = 0; s < 4; ++s) {
            const float* src = Qb + (size_t)qrow * DH + 16 * s + 8 * hl;
            f32x4 qa = *(const f32x4*)src;
            f32x4 qb = *(const f32x4*)(src + 4);
            union { unsigned u[4]; short8 v; } f;
            f.u[0] = pk2bf(qa[0] * qscale, qa[1] * qscale);
            f.u[1] = pk2bf(qa[2] * qscale, qa[3] * qscale);
            f.u[2] = pk2bf(qb[0] * qscale, qb[1] * qscale);
            f.u[3] = pk2bf(qb[2] * qscale, qb[3] * qscale);
            qf[s] = f.v;
        }
    }

    // ---- staging source pointers (lane-constant swizzle) ----
    const int gk = (lane & 7) ^ (lane >> 3);
    const int rr = w * 8 + (lane >> 3);
    const short* kg0 = Kbh + (size_t)rr * DH + gk * 8;
    const short* kg1 = kg0 + 32 * DH;
    const short* vg0 = Vbh + (size_t)rr * SQ + gk * 8;
    const short* vg1 = vg0 + 32 * SQ;
    const int wslot = w * 1024;   // scalar

    // ---- loop-invariant per-lane LDS frag addresses (bytes) ----
    int aoff[4];
    #pragma unroll
    for (int s = 0; s < 4; ++s) aoff[s] = m31 * 128 + (((2 * s + hl) ^ l7) * 16);

    f32x16 o0 = {}, o1 = {};
    f32x2 lp2 = {0.f, 0.f};

    // issue K tile t into Kbuf[slot] (2 KB/wave via DMA)
    auto issueK = [&](int slot, int t) {
        const short* p0 = kg0 + (size_t)t * (KTILE * DH);
        const short* p1 = kg1 + (size_t)t * (KTILE * DH);
        load_lds16(p0, L + slot * 8192 + wslot);
        load_lds16(p1, L + slot * 8192 + 4096 + wslot);
    };
    // issue V tile t into Vbuf[slot]
    auto issueV = [&](int slot, int t) {
        const short* p0 = vg0 + (size_t)t * KTILE;
        const short* p1 = vg1 + (size_t)t * KTILE;
        load_lds16(p0, L + 16384 + slot * 8192 + wslot);
        load_lds16(p1, L + 16384 + slot * 8192 + 4096 + wslot);
    };

    // exp + in-register C->A relayout; consumes one f32x16 S half
    auto softmax_pack = [&](const f32x16& sv, short8* dst) {
        #pragma unroll
        for (int wd = 0; wd < 2; ++wd) {
            float p[8];
            #pragma unroll
            for (int j = 0; j < 8; ++j)
                p[j] = __builtin_amdgcn_exp2f(sv[8 * wd + j]);
            // row-sum via packed v_pk_add_f32
            f32x2 s01 = {p[0], p[1]}, s23 = {p[2], p[3]};
            f32x2 s45 = {p[4], p[5]}, s67 = {p[6], p[7]};
            lp2 += (s01 + s23) + (s45 + s67);
            unsigned a0 = pk2bf(p[0], p[1]);   // kk 4hl+{0,1}
            unsigned a1 = pk2bf(p[2], p[3]);   // kk 4hl+{2,3}
            unsigned b0 = pk2bf(p[4], p[5]);   // kk 8+4hl+{0,1}
            unsigned b1 = pk2bf(p[6], p[7]);   // kk 8+4hl+{2,3}
            union { unsigned u[4]; short8 v; } fr;
#if HAVE_PLSWAP
            // v_permlane32_swap_b32: swaps upper 32 lanes of vdst with lower 32 of vsrc.
            // r.x = {lo: a[0:31]  | hi: b[0:31]}  = A-frag word0
            // r.y = {lo: a[32:63] | hi: b[32:63]} = A-frag word2
            i32x2 r0 = __builtin_amdgcn_permlane32_swap((int)a0, (int)b0, false, false);
            i32x2 r1 = __builtin_amdgcn_permlane32_swap((int)a1, (int)b1, false, false);
            fr.u[0] = (unsigned)r0.x;
            fr.u[1] = (unsigned)r1.x;
            fr.u[2] = (unsigned)r0.y;
            fr.u[3] = (unsigned)r1.y;
#else
            unsigned r0 = (unsigned)__shfl_xor((int)(hl ? a0 : b0), 32, 64);
            unsigned r1 = (unsigned)__shfl_xor((int)(hl ? a1 : b1), 32, 64);
            fr.u[0] = hl ? r0 : a0;
            fr.u[1] = hl ? r1 : a1;
            fr.u[2] = hl ? b0 : r0;
            fr.u[3] = hl ? b1 : r1;
#endif
            dst[wd] = fr.v;
        }
    };

    // QK^T for one K-tile from Kbuf[slot] -> two 32x32 score tiles
    auto qk = [&](int slot, f32x16& t0, f32x16& t1) {
        f32x16 a0 = {}, a1 = {};
        #pragma unroll
        for (int s = 0; s < 4; ++s) {
            short8 ka0 = *(const short8*)(L + slot * 8192 + aoff[s]);
            short8 ka1 = *(const short8*)(L + slot * 8192 + 4096 + aoff[s]);
            a0 = MFMA32(ka0, qf[s], a0);
            a1 = MFMA32(ka1, qf[s], a1);
        }
        t0 = a0; t1 = a1;
    };

    // softmax of previous tile's scores + PV accumulate from Vbuf[slot]
    auto smpv = [&](int slot, const f32x16& sc0, const f32x16& sc1) {
        short8 pf[4];
        softmax_pack(sc0, &pf[0]);
        softmax_pack(sc1, &pf[2]);
        #pragma unroll
        for (int s = 0; s < 4; ++s) {
            short8 vb0 = *(const short8*)(L + 16384 + slot * 8192 + aoff[s]);
            short8 vb1 = *(const short8*)(L + 16384 + slot * 8192 + 4096 + aoff[s]);
            o0 = MFMA32(pf[s], vb0, o0);
            o1 = MFMA32(pf[s], vb1, o1);
        }
    };

    // ---- prologue: K0,V0,K1 in flight; QK(0) computed ----
    issueK(0, 0); issueV(0, 0); issueK(1, 1);
    __syncthreads();
    f32x16 sc0, sc1;
    qk(0, sc0, sc1);

    // ---- pipelined main loop: iter t does QK(t+1), SM(t), PV(t) ----
    // Buffer safety: sync at top of iter t guarantees all waves finished iter t-1,
    // i.e. QK(t) done -> Kbuf[t&1] (holding K(t)) is dead and may take K(t+2);
    // PV(t-1) done -> Vbuf[(t+1)&1] (holding V(t-1)) may take V(t+1).
    #pragma unroll 2
    for (int t = 0; t < NITER - 1; ++t) {
        __syncthreads();                       // drains K(t+1),V(t) DMAs (issued iter t-1)
        if (t + 2 < NITER) issueK(t & 1, t + 2);
        issueV((t + 1) & 1, t + 1);
        f32x16 sn0, sn1;
        qk((t + 1) & 1, sn0, sn1);             // MFMA, independent of SM below
        smpv(t & 1, sc0, sc1);                 // VALU softmax overlaps qk's waits
        sc0 = sn0; sc1 = sn1;
    }
    __syncthreads();                           // V(NITER-1) DMA drained
    smpv((NITER - 1) & 1, sc0, sc1);

    // ---- finalize: l(q=m31) = lp(lane) + lp(lane^32); invert; scatter ----
    float lp = lp2.x + lp2.y;
    float v = lp;
    v += __shfl_xor(v, 32, 64);
    const float linv = 1.0f / v;

    #pragma unroll
    for (int dt = 0; dt < 2; ++dt) {
        const f32x16& o = dt ? o1 : o0;
        #pragma unroll
        for (int reg = 0; reg < 16; ++reg) {
            const int qp = (reg & 3) + 8 * (reg >> 2) + 4 * hl;
            const float rl = __shfl(linv, qp, 64);
            const int q = q0 + 32 * w + qp;
            Ob[(size_t)q * DH + 32 * dt + m31] = o[reg] * rl;
        }
    }
}

extern "C" void kernel_launch(void* const* d_in, const int* in_sizes, int n_in,
                              void* d_out, int out_size, void* d_ws, size_t ws_size,
                              hipStream_t stream) {
    const float* Q = (const float*)d_in[0];
    const float* K = (const float*)d_in[1];
    const float* V = (const float*)d_in[2];
    float* O = (float*)d_out;

    // workspace: bf16 K (12.6 MB) + bf16 V^T (12.6 MB)
    short* Kb  = (short*)d_ws;
    short* Vtg = Kb + (size_t)NBH * SQ * DH;

    prepass<<<dim3(KCONV_BLOCKS + NBH * 32), dim3(256), 0, stream>>>(K, Kb, V, Vtg);
    // 768 blocks, XCD-swizzled (head-locality in per-XCD L2); 32 KB LDS, 3 blocks/CU
    attn_fused_kernel<<<dim3(NBH * NQT), dim3(256), 0, stream>>>(Q, Kb, Vtg, O);
}

// Round 3
// 511.410 us; speedup vs baseline: 1.0122x; 1.0122x over previous
//
#include <hip/hip_runtime.h>

#define SQ 2048
#define DH 64
#define NH 12
#define NBH 48          // B*H
#define QTILE 128       // q rows per block (32 per wave)
#define KTILE 64        // keys per iteration
#define NITER (SQ / KTILE)
#define NQT (SQ / QTILE)   // 16 q-tiles -> 768 blocks = 3 blocks/CU

typedef short short8 __attribute__((ext_vector_type(8)));
typedef float f32x2  __attribute__((ext_vector_type(2)));
typedef float f32x4  __attribute__((ext_vector_type(4)));
typedef float f32x16 __attribute__((ext_vector_type(16)));
typedef int   i32x2 __attribute__((ext_vector_type(2)));
typedef int   i32x4 __attribute__((ext_vector_type(4)));

#define MFMA32(a, b, c) __builtin_amdgcn_mfma_f32_32x32x16_bf16(a, b, c, 0, 0, 0)

typedef __attribute__((address_space(1))) const void* gas_ptr;
typedef __attribute__((address_space(3))) void* las_ptr;

__device__ __forceinline__ void load_lds16(const void* g, void* l) {
    // 16B/lane direct global->LDS DMA; LDS dest = wave-uniform base + lane*16
    __builtin_amdgcn_global_load_lds((gas_ptr)g, (las_ptr)l, 16, 0, 0);
}

// two fp32 -> packed bf16x2 (low = a, high = b), RTNE
#if defined(__has_builtin) && __has_builtin(__builtin_amdgcn_cvt_pk_bf16_f32)
typedef __bf16 bf16x2_t __attribute__((ext_vector_type(2)));
__device__ __forceinline__ unsigned pk2bf(float a, float b) {
    bf16x2_t v = __builtin_amdgcn_cvt_pk_bf16_f32(a, b);
    union { bf16x2_t v; unsigned u; } c; c.v = v; return c.u;
}
#else
__device__ __forceinline__ unsigned pk2bf(float a, float b) {
    union { float f; unsigned u; } x, y; x.f = a; y.f = b;
    unsigned ra = x.u + 0x7FFFu + ((x.u >> 16) & 1u);
    unsigned rb = y.u + 0x7FFFu + ((y.u >> 16) & 1u);
    return (ra >> 16) | (rb & 0xFFFF0000u);
}
#endif

#ifdef __has_builtin
#if __has_builtin(__builtin_amdgcn_permlane32_swap)
#define HAVE_PLSWAP 1
#else
#define HAVE_PLSWAP 0
#endif
#else
#define HAVE_PLSWAP 0
#endif

// ------- fused pre-pass: K fp32->bf16 (blocks 0..3071)  |  V transpose (rest) -------
#define KCONV_BLOCKS (NBH * SQ * DH / 8 / 256)   // 3072
__global__ __launch_bounds__(256)
void prepass(const float* __restrict__ K, short* __restrict__ Kb,
             const float* __restrict__ V, short* __restrict__ Vt) {
    __shared__ float Ls[64][68];   // transpose staging (+4 pad)
    if (blockIdx.x < KCONV_BLOCKS) {
        const size_t i = (size_t)(blockIdx.x * 256 + threadIdx.x) * 8;
        f32x4 a = *(const f32x4*)&K[i];
        f32x4 b = *(const f32x4*)&K[i + 4];
        unsigned o[4] = { pk2bf(a[0], a[1]), pk2bf(a[2], a[3]),
                          pk2bf(b[0], b[1]), pk2bf(b[2], b[3]) };
        *(i32x4*)&Kb[i] = *(i32x4*)o;
        return;
    }
    const int bx = blockIdx.x - KCONV_BLOCKS;
    const int st = bx & 31;       // s tile
    const int bh = bx >> 5;
    const int b = bh / NH, h = bh % NH;
    const int s0 = st * 64;
    const float* src = V + ((size_t)b * SQ * NH + (size_t)h) * DH;
    const int dg = threadIdx.x & 15;   // d = 4*dg
    const int sl = threadIdx.x >> 4;   // 0..15
    #pragma unroll
    for (int p = 0; p < 4; ++p) {
        const int row = p * 16 + sl;
        *(f32x4*)&Ls[row][dg * 4] =
            *(const f32x4*)&src[(size_t)(s0 + row) * (NH * DH) + dg * 4];
    }
    __syncthreads();
    const int dr = threadIdx.x >> 2;        // d row 0..63
    const int sc = (threadIdx.x & 3) * 16;  // s chunk
    unsigned out[8];
    #pragma unroll
    for (int jj = 0; jj < 8; ++jj)
        out[jj] = pk2bf(Ls[sc + 2 * jj][dr], Ls[sc + 2 * jj + 1][dr]);
    short* dst = Vt + (size_t)bh * DH * SQ + (size_t)dr * SQ + s0 + sc;
    *(i32x4*)(dst)     = *(i32x4*)&out[0];
    *(i32x4*)(dst + 8) = *(i32x4*)&out[4];
}

// ---------------- main fused attention (32x32x16 MFMA, P-carry pipeline) ----------------
// Iter t: {sync; DMA K(t+2),V(t+1); QK(t+1)->sn [MFMA]; PV(t) from carried pf [MFMA,
// independent -> issues while sn completes]; pf = softmax(sn) [VALU, stall covered by PV]}.
// Carried state is only the PACKED P (4x short8 = 16 VGPR), not raw scores (r1 carried
// 64 VGPR of f32x16 scores -> spilled ~4KB/thread to scratch -> 790 MB HBM writes, 5x).
__global__ __launch_bounds__(256, 3)
void attn_fused_kernel(const float* __restrict__ Q,
                       const short* __restrict__ Kb,   // bf16 [BH][S][D]
                       const short* __restrict__ Vtg,  // bf16 [BH][D][S]
                       float* __restrict__ O) {
    // Flat LDS arena:
    //   Kbuf[i] at i*8192       (halves +0 rows0-31, +4096 rows32-63)
    //   Vbuf[i] at 16384+i*8192 (halves +0 d0-31,    +4096 d32-63)
    // XOR chunk swizzle (chunk c of row r at c^(r&7)); unpadded 128B rows.
    __shared__ __align__(16) char L[32768];

    const int tid  = threadIdx.x;
    const int lane = tid & 63;
    const int w    = tid >> 6;
    const int m31  = lane & 31;     // MFMA row/col index
    const int hl   = lane >> 5;     // half-wave 0/1
    const int l7   = lane & 7;

    // ---- XCD-locality swizzle: dispatch round-robins XCDs by (bx & 7).
    const int bx  = blockIdx.x;
    const int xcd = bx & 7;
    const int i96 = bx >> 3;          // 0..95
    const int bh  = xcd * 6 + (i96 % 6);
    const int qt  = i96 / 6;          // 0..15
    const int q0 = qt * QTILE;

    const float* Qb  = Q   + (size_t)bh * SQ * DH;
    const short* Kbh = Kb  + (size_t)bh * SQ * DH;
    const short* Vbh = Vtg + (size_t)bh * DH * SQ;
    float*       Ob  = O   + (size_t)bh * SQ * DH;

    // scale folded into Q, exp as exp2: 1/sqrt(768) * log2(e)
    const float qscale = 0.03608439182435161f * 1.4426950408889634f;

    // ---- Q fragments (B operand: n=m31 -> q row, k=16*s+8*hl+j) ----
    short8 qf[4];
    {
        const int qrow = q0 + 32 * w + m31;
        #pragma unroll
        for (int s = 0; s < 4; ++s) {
            const float* src = Qb + (size_t)qrow * DH + 16 * s + 8 * hl;
            f32x4 qa = *(const f32x4*)src;
            f32x4 qb = *(const f32x4*)(src + 4);
            union { unsigned u[4]; short8 v; } f;
            f.u[0] = pk2bf(qa[0] * qscale, qa[1] * qscale);
            f.u[1] = pk2bf(qa[2] * qscale, qa[3] * qscale);
            f.u[2] = pk2bf(qb[0] * qscale, qb[1] * qscale);
            f.u[3] = pk2bf(qb[2] * qscale, qb[3] * qscale);
            qf[s] = f.v;
        }
    }

    // ---- staging source pointers (lane-constant swizzle) ----
    const int gk = (lane & 7) ^ (lane >> 3);
    const int rr = w * 8 + (lane >> 3);
    const short* kg0 = Kbh + (size_t)rr * DH + gk * 8;
    const short* kg1 = kg0 + 32 * DH;
    const short* vg0 = Vbh + (size_t)rr * SQ + gk * 8;
    const short* vg1 = vg0 + 32 * SQ;
    const int wslot = w * 1024;   // scalar

    // ---- loop-invariant per-lane LDS frag addresses (bytes) ----
    int aoff[4];
    #pragma unroll
    for (int s = 0; s < 4; ++s) aoff[s] = m31 * 128 + (((2 * s + hl) ^ l7) * 16);

    f32x16 o0 = {}, o1 = {};
    f32x2 lp2 = {0.f, 0.f};

    struct SC2 { f32x16 a, b; };
    struct PFrag { short8 lo, hi; };
    struct PF { short8 p0, p1, p2, p3; };   // carried packed P (16 VGPR)

    // issue K tile t into Kbuf[slot] (2 KB/wave via DMA)
    auto issueK = [&](int slot, int t) {
        const short* p0 = kg0 + (size_t)t * (KTILE * DH);
        const short* p1 = kg1 + (size_t)t * (KTILE * DH);
        load_lds16(p0, L + slot * 8192 + wslot);
        load_lds16(p1, L + slot * 8192 + 4096 + wslot);
    };
    // issue V tile t into Vbuf[slot]
    auto issueV = [&](int slot, int t) {
        const short* p0 = vg0 + (size_t)t * KTILE;
        const short* p1 = vg1 + (size_t)t * KTILE;
        load_lds16(p0, L + 16384 + slot * 8192 + wslot);
        load_lds16(p1, L + 16384 + slot * 8192 + 4096 + wslot);
    };

    // exp + in-register C->A relayout; consumes one f32x16 S half, returns 2 A-frags
    auto softmax_pack = [&](const f32x16 sv) {
        short8 d[2];
        #pragma unroll
        for (int wd = 0; wd < 2; ++wd) {
            float p[8];
            #pragma unroll
            for (int j = 0; j < 8; ++j)
                p[j] = __builtin_amdgcn_exp2f(sv[8 * wd + j]);
            // row-sum via packed v_pk_add_f32
            f32x2 s01 = {p[0], p[1]}, s23 = {p[2], p[3]};
            f32x2 s45 = {p[4], p[5]}, s67 = {p[6], p[7]};
            lp2 += (s01 + s23) + (s45 + s67);
            unsigned a0 = pk2bf(p[0], p[1]);   // kk 4hl+{0,1}
            unsigned a1 = pk2bf(p[2], p[3]);   // kk 4hl+{2,3}
            unsigned b0 = pk2bf(p[4], p[5]);   // kk 8+4hl+{0,1}
            unsigned b1 = pk2bf(p[6], p[7]);   // kk 8+4hl+{2,3}
            union { unsigned u[4]; short8 v; } fr;
#if HAVE_PLSWAP
            // r.x = {lo: a[0:31]  | hi: b[0:31]}  = A-frag word0
            // r.y = {lo: a[32:63] | hi: b[32:63]} = A-frag word2
            i32x2 r0 = __builtin_amdgcn_permlane32_swap((int)a0, (int)b0, false, false);
            i32x2 r1 = __builtin_amdgcn_permlane32_swap((int)a1, (int)b1, false, false);
            fr.u[0] = (unsigned)r0.x;
            fr.u[1] = (unsigned)r1.x;
            fr.u[2] = (unsigned)r0.y;
            fr.u[3] = (unsigned)r1.y;
#else
            unsigned r0 = (unsigned)__shfl_xor((int)(hl ? a0 : b0), 32, 64);
            unsigned r1 = (unsigned)__shfl_xor((int)(hl ? a1 : b1), 32, 64);
            fr.u[0] = hl ? r0 : a0;
            fr.u[1] = hl ? r1 : a1;
            fr.u[2] = hl ? b0 : r0;
            fr.u[3] = hl ? b1 : r1;
#endif
            d[wd] = fr.v;
        }
        return PFrag{d[0], d[1]};
    };

    auto softmax2 = [&](const SC2 s) {
        PFrag f0 = softmax_pack(s.a);
        PFrag f1 = softmax_pack(s.b);
        return PF{f0.lo, f0.hi, f1.lo, f1.hi};
    };

    // QK^T for one K-tile from Kbuf[slot] -> two 32x32 score tiles (by value)
    auto qk = [&](int slot) {
        f32x16 a0 = {}, a1 = {};
        #pragma unroll
        for (int s = 0; s < 4; ++s) {
            short8 ka0 = *(const short8*)(L + slot * 8192 + aoff[s]);
            short8 ka1 = *(const short8*)(L + slot * 8192 + 4096 + aoff[s]);
            a0 = MFMA32(ka0, qf[s], a0);
            a1 = MFMA32(ka1, qf[s], a1);
        }
        return SC2{a0, a1};
    };

    // PV accumulate from Vbuf[slot] with carried packed P
    auto opv = [&](int slot, const PF f) {
        const char* Vb = L + 16384 + slot * 8192;
        o0 = MFMA32(f.p0, *(const short8*)(Vb + aoff[0]), o0);
        o1 = MFMA32(f.p0, *(const short8*)(Vb + 4096 + aoff[0]), o1);
        o0 = MFMA32(f.p1, *(const short8*)(Vb + aoff[1]), o0);
        o1 = MFMA32(f.p1, *(const short8*)(Vb + 4096 + aoff[1]), o1);
        o0 = MFMA32(f.p2, *(const short8*)(Vb + aoff[2]), o0);
        o1 = MFMA32(f.p2, *(const short8*)(Vb + 4096 + aoff[2]), o1);
        o0 = MFMA32(f.p3, *(const short8*)(Vb + aoff[3]), o0);
        o1 = MFMA32(f.p3, *(const short8*)(Vb + 4096 + aoff[3]), o1);
    };

    // ---- prologue: K0,V0,K1 in flight; P(0) computed ----
    issueK(0, 0); issueV(0, 0); issueK(1, 1);
    __syncthreads();
    PF pf = softmax2(qk(0));

    // ---- pipelined main loop ----
    // Barrier at top of iter t: all waves finished QK(t) (so Kbuf[t&1] is dead and may
    // take K(t+2)) and PV(t-1) (so Vbuf[(t+1)&1] may take V(t+1)); drains the K(t+1)
    // and V(t) DMAs issued in iter t-1 (prologue for t=0).
    #pragma unroll 2
    for (int t = 0; t < NITER - 1; ++t) {
        __syncthreads();
        if (t + 2 < NITER) issueK(t & 1, t + 2);
        issueV((t + 1) & 1, t + 1);
        SC2 sn = qk((t + 1) & 1);   // MFMA on K(t+1), ready
        opv(t & 1, pf);             // PV(t): independent MFMA, issues under sn's latency
        pf = softmax2(sn);          // VALU; sn-stall covered by PV's in-flight MFMAs
    }
    __syncthreads();                // drains V(NITER-1)
    opv((NITER - 1) & 1, pf);       // PV(NITER-1)

    // ---- finalize: l(q=m31) = lp(lane) + lp(lane^32); invert; scatter ----
    float lp = lp2.x + lp2.y;
    float v = lp;
    v += __shfl_xor(v, 32, 64);
    const float linv = 1.0f / v;

    #pragma unroll
    for (int dt = 0; dt < 2; ++dt) {
        const f32x16& o = dt ? o1 : o0;
        #pragma unroll
        for (int reg = 0; reg < 16; ++reg) {
            const int qp = (reg & 3) + 8 * (reg >> 2) + 4 * hl;
            const float rl = __shfl(linv, qp, 64);
            const int q = q0 + 32 * w + qp;
            Ob[(size_t)q * DH + 32 * dt + m31] = o[reg] * rl;
        }
    }
}

extern "C" void kernel_launch(void* const* d_in, const int* in_sizes, int n_in,
                              void* d_out, int out_size, void* d_ws, size_t ws_size,
                              hipStream_t stream) {
    const float* Q = (const float*)d_in[0];
    const float* K = (const float*)d_in[1];
    const float* V = (const float*)d_in[2];
    float* O = (float*)d_out;

    // workspace: bf16 K (12.6 MB) + bf16 V^T (12.6 MB)
    short* Kb  = (short*)d_ws;
    short* Vtg = Kb + (size_t)NBH * SQ * DH;

    prepass<<<dim3(KCONV_BLOCKS + NBH * 32), dim3(256), 0, stream>>>(K, Kb, V, Vtg);
    // 768 blocks, XCD-swizzled (head-locality in per-XCD L2); 32 KB LDS, 3 blocks/CU
    attn_fused_kernel<<<dim3(NBH * NQT), dim3(256), 0, stream>>>(Q, Kb, Vtg, O);
}

// Round 4
// 177.326 us; speedup vs baseline: 2.9192x; 2.8840x over previous
//
#include <hip/hip_runtime.h>

#define SQ 2048
#define DH 64
#define NH 12
#define NBH 48          // B*H
#define QTILE 128       // q rows per block (32 per wave)
#define KTILE 64        // keys per iteration
#define NITER (SQ / KTILE)
#define NQT (SQ / QTILE)   // 16 q-tiles -> 768 blocks = 3 blocks/CU

// LDS arena bases (literal)
#define KB0 0
#define KB1 8192
#define VB0 16384
#define VB1 24576

typedef short short8 __attribute__((ext_vector_type(8)));
typedef float f32x2  __attribute__((ext_vector_type(2)));
typedef float f32x4  __attribute__((ext_vector_type(4)));
typedef float f32x16 __attribute__((ext_vector_type(16)));
typedef int   i32x2 __attribute__((ext_vector_type(2)));
typedef int   i32x4 __attribute__((ext_vector_type(4)));

#define MFMA32(a, b, c) __builtin_amdgcn_mfma_f32_32x32x16_bf16(a, b, c, 0, 0, 0)

typedef __attribute__((address_space(1))) const void* gas_ptr;
typedef __attribute__((address_space(3))) void* las_ptr;

__device__ __forceinline__ void load_lds16(const void* g, void* l) {
    // 16B/lane direct global->LDS DMA; LDS dest = wave-uniform base + lane*16
    __builtin_amdgcn_global_load_lds((gas_ptr)g, (las_ptr)l, 16, 0, 0);
}

// two fp32 -> packed bf16x2 (low = a, high = b), RTNE
#if defined(__has_builtin) && __has_builtin(__builtin_amdgcn_cvt_pk_bf16_f32)
typedef __bf16 bf16x2_t __attribute__((ext_vector_type(2)));
__device__ __forceinline__ unsigned pk2bf(float a, float b) {
    bf16x2_t v = __builtin_amdgcn_cvt_pk_bf16_f32(a, b);
    union { bf16x2_t v; unsigned u; } c; c.v = v; return c.u;
}
#else
__device__ __forceinline__ unsigned pk2bf(float a, float b) {
    union { float f; unsigned u; } x, y; x.f = a; y.f = b;
    unsigned ra = x.u + 0x7FFFu + ((x.u >> 16) & 1u);
    unsigned rb = y.u + 0x7FFFu + ((y.u >> 16) & 1u);
    return (ra >> 16) | (rb & 0xFFFF0000u);
}
#endif

#ifdef __has_builtin
#if __has_builtin(__builtin_amdgcn_permlane32_swap)
#define HAVE_PLSWAP 1
#else
#define HAVE_PLSWAP 0
#endif
#else
#define HAVE_PLSWAP 0
#endif

// ------- fused pre-pass: K fp32->bf16 (blocks 0..3071)  |  V transpose (rest) -------
#define KCONV_BLOCKS (NBH * SQ * DH / 8 / 256)   // 3072
__global__ __launch_bounds__(256)
void prepass(const float* __restrict__ K, short* __restrict__ Kb,
             const float* __restrict__ V, short* __restrict__ Vt) {
    __shared__ float Ls[64][68];   // transpose staging (+4 pad)
    if (blockIdx.x < KCONV_BLOCKS) {
        const size_t i = (size_t)(blockIdx.x * 256 + threadIdx.x) * 8;
        f32x4 a = *(const f32x4*)&K[i];
        f32x4 b = *(const f32x4*)&K[i + 4];
        unsigned o[4] = { pk2bf(a[0], a[1]), pk2bf(a[2], a[3]),
                          pk2bf(b[0], b[1]), pk2bf(b[2], b[3]) };
        *(i32x4*)&Kb[i] = *(i32x4*)o;
        return;
    }
    const int bx = blockIdx.x - KCONV_BLOCKS;
    const int st = bx & 31;       // s tile
    const int bh = bx >> 5;
    const int b = bh / NH, h = bh % NH;
    const int s0 = st * 64;
    const float* src = V + ((size_t)b * SQ * NH + (size_t)h) * DH;
    const int dg = threadIdx.x & 15;   // d = 4*dg
    const int sl = threadIdx.x >> 4;   // 0..15
    #pragma unroll
    for (int p = 0; p < 4; ++p) {
        const int row = p * 16 + sl;
        *(f32x4*)&Ls[row][dg * 4] =
            *(const f32x4*)&src[(size_t)(s0 + row) * (NH * DH) + dg * 4];
    }
    __syncthreads();
    const int dr = threadIdx.x >> 2;        // d row 0..63
    const int sc = (threadIdx.x & 3) * 16;  // s chunk
    unsigned out[8];
    #pragma unroll
    for (int jj = 0; jj < 8; ++jj)
        out[jj] = pk2bf(Ls[sc + 2 * jj][dr], Ls[sc + 2 * jj + 1][dr]);
    short* dst = Vt + (size_t)bh * DH * SQ + (size_t)dr * SQ + s0 + sc;
    *(i32x4*)(dst)     = *(i32x4*)&out[0];
    *(i32x4*)(dst + 8) = *(i32x4*)&out[4];
}

// ---------------- main fused attention (32x32x16 MFMA, P-carry pipeline) ----------------
// Iter t: {sync; DMA K(t+2),V(t+1); QK(t+1)->sn [MFMA]; PV(t) from pfc [independent MFMA,
// issues under sn's latency]; pfc = softmax(sn) [VALU]}.
// NO aggregate passing through lambdas: r1/r2 passed the 128B score pair as ref-out /
// by-value struct -> failed SROA -> per-iter scratch store/reload (791 MB HBM writes,
// VGPR stuck at 84). All state here is captured named variables + constant-indexed
// arrays (the baseline's proven-clean codegen idioms); loop manually unrolled x2 with
// literal LDS bases.
__global__ __launch_bounds__(256, 3)
void attn_fused_kernel(const float* __restrict__ Q,
                       const short* __restrict__ Kb,   // bf16 [BH][S][D]
                       const short* __restrict__ Vtg,  // bf16 [BH][D][S]
                       float* __restrict__ O) {
    // Kbuf j at KB(j&1) (halves +0 rows0-31, +4096 rows32-63)
    // Vbuf j at VB(j&1) (halves +0 d0-31,    +4096 d32-63)
    // XOR chunk swizzle (chunk c of row r at c^(r&7)); unpadded 128B rows.
    __shared__ __align__(16) char L[32768];

    const int tid  = threadIdx.x;
    const int lane = tid & 63;
    const int w    = tid >> 6;
    const int m31  = lane & 31;     // MFMA row/col index
    const int hl   = lane >> 5;     // half-wave 0/1
    const int l7   = lane & 7;

    // ---- XCD-locality swizzle: dispatch round-robins XCDs by (bx & 7).
    const int bx  = blockIdx.x;
    const int xcd = bx & 7;
    const int i96 = bx >> 3;          // 0..95
    const int bh  = xcd * 6 + (i96 % 6);
    const int qt  = i96 / 6;          // 0..15
    const int q0 = qt * QTILE;

    const float* Qb  = Q   + (size_t)bh * SQ * DH;
    const short* Kbh = Kb  + (size_t)bh * SQ * DH;
    const short* Vbh = Vtg + (size_t)bh * DH * SQ;
    float*       Ob  = O   + (size_t)bh * SQ * DH;

    // scale folded into Q, exp as exp2: 1/sqrt(768) * log2(e)
    const float qscale = 0.03608439182435161f * 1.4426950408889634f;

    // ---- Q fragments (B operand: n=m31 -> q row, k=16*s+8*hl+j) ----
    short8 qf[4];
    {
        const int qrow = q0 + 32 * w + m31;
        #pragma unroll
        for (int s = 0; s < 4; ++s) {
            const float* src = Qb + (size_t)qrow * DH + 16 * s + 8 * hl;
            f32x4 qa = *(const f32x4*)src;
            f32x4 qb = *(const f32x4*)(src + 4);
            union { unsigned u[4]; short8 v; } f;
            f.u[0] = pk2bf(qa[0] * qscale, qa[1] * qscale);
            f.u[1] = pk2bf(qa[2] * qscale, qa[3] * qscale);
            f.u[2] = pk2bf(qb[0] * qscale, qb[1] * qscale);
            f.u[3] = pk2bf(qb[2] * qscale, qb[3] * qscale);
            qf[s] = f.v;
        }
    }

    // ---- staging source pointers (lane-constant swizzle) ----
    const int gk = (lane & 7) ^ (lane >> 3);
    const int rr = w * 8 + (lane >> 3);
    const short* kg0 = Kbh + (size_t)rr * DH + gk * 8;
    const short* kg1 = kg0 + 32 * DH;
    const short* vg0 = Vbh + (size_t)rr * SQ + gk * 8;
    const short* vg1 = vg0 + 32 * SQ;
    const int wslot = w * 1024;   // scalar

    // ---- loop-invariant per-lane LDS frag addresses (bytes) ----
    int aoff[4];
    #pragma unroll
    for (int s = 0; s < 4; ++s) aoff[s] = m31 * 128 + (((2 * s + hl) ^ l7) * 16);

    // ---- pipeline state: all captured named vars / constant-indexed arrays ----
    f32x16 o0 = {}, o1 = {};   // output accumulators
    f32x16 sn0, sn1;           // scores of the tile being softmaxed next
    short8 pfc[4];             // carried packed P fragments
    f32x2 lp2 = {0.f, 0.f};    // row-sum accumulator (packed)

    // issue K tile t into Kbuf base kb (2 KB/wave via DMA)
    auto issueK = [&](int kb, int t) {
        const short* p0 = kg0 + (size_t)t * (KTILE * DH);
        const short* p1 = kg1 + (size_t)t * (KTILE * DH);
        load_lds16(p0, L + kb + wslot);
        load_lds16(p1, L + kb + 4096 + wslot);
    };
    // issue V tile t into Vbuf base vb
    auto issueV = [&](int vb, int t) {
        const short* p0 = vg0 + (size_t)t * KTILE;
        const short* p1 = vg1 + (size_t)t * KTILE;
        load_lds16(p0, L + vb + wslot);
        load_lds16(p1, L + vb + 4096 + wslot);
    };

    // QK^T from Kbuf base kb -> writes captured sn0, sn1
    auto qk = [&](int kb) {
        f32x16 a0 = {}, a1 = {};
        #pragma unroll
        for (int s = 0; s < 4; ++s) {
            short8 ka0 = *(const short8*)(L + kb + aoff[s]);
            short8 ka1 = *(const short8*)(L + kb + 4096 + aoff[s]);
            a0 = MFMA32(ka0, qf[s], a0);
            a1 = MFMA32(ka1, qf[s], a1);
        }
        sn0 = a0; sn1 = a1;
    };

    // exp + in-register C->A relayout; consumes one score half into dst[0..1]
    auto softmax_pack = [&](const f32x16& sv, short8* dst) {
        #pragma unroll
        for (int wd = 0; wd < 2; ++wd) {
            float p[8];
            #pragma unroll
            for (int j = 0; j < 8; ++j)
                p[j] = __builtin_amdgcn_exp2f(sv[8 * wd + j]);
            // row-sum via packed v_pk_add_f32
            f32x2 s01 = {p[0], p[1]}, s23 = {p[2], p[3]};
            f32x2 s45 = {p[4], p[5]}, s67 = {p[6], p[7]};
            lp2 += (s01 + s23) + (s45 + s67);
            unsigned a0 = pk2bf(p[0], p[1]);   // kk 4hl+{0,1}
            unsigned a1 = pk2bf(p[2], p[3]);   // kk 4hl+{2,3}
            unsigned b0 = pk2bf(p[4], p[5]);   // kk 8+4hl+{0,1}
            unsigned b1 = pk2bf(p[6], p[7]);   // kk 8+4hl+{2,3}
            union { unsigned u[4]; short8 v; } fr;
#if HAVE_PLSWAP
            // r.x = {lo: a[0:31]  | hi: b[0:31]}  = A-frag word0
            // r.y = {lo: a[32:63] | hi: b[32:63]} = A-frag word2
            i32x2 r0 = __builtin_amdgcn_permlane32_swap((int)a0, (int)b0, false, false);
            i32x2 r1 = __builtin_amdgcn_permlane32_swap((int)a1, (int)b1, false, false);
            fr.u[0] = (unsigned)r0.x;
            fr.u[1] = (unsigned)r1.x;
            fr.u[2] = (unsigned)r0.y;
            fr.u[3] = (unsigned)r1.y;
#else
            unsigned r0 = (unsigned)__shfl_xor((int)(hl ? a0 : b0), 32, 64);
            unsigned r1 = (unsigned)__shfl_xor((int)(hl ? a1 : b1), 32, 64);
            fr.u[0] = hl ? r0 : a0;
            fr.u[1] = hl ? r1 : a1;
            fr.u[2] = hl ? b0 : r0;
            fr.u[3] = hl ? b1 : r1;
#endif
            dst[wd] = fr.v;
        }
    };
    // softmax both score halves -> pfc[0..3]
    auto softmax2 = [&]() {
        softmax_pack(sn0, &pfc[0]);
        softmax_pack(sn1, &pfc[2]);
    };

    // PV accumulate from Vbuf base vb with carried pfc
    auto pv = [&](int vb) {
        #pragma unroll
        for (int s = 0; s < 4; ++s) {
            short8 vv0 = *(const short8*)(L + vb + aoff[s]);
            short8 vv1 = *(const short8*)(L + vb + 4096 + aoff[s]);
            o0 = MFMA32(pfc[s], vv0, o0);
            o1 = MFMA32(pfc[s], vv1, o1);
        }
    };

    // ---- prologue: K0,V0,K1 in flight; pfc = P(0) ----
    issueK(KB0, 0); issueV(VB0, 0); issueK(KB1, 1);
    __syncthreads();
    qk(KB0);
    softmax2();

    // ---- pipelined main loop, manually unrolled x2 (tiles t..t+1), literal bases ----
    // Barrier at top of each half: all waves finished the previous half's QK/PV, so the
    // buffer being overwritten is dead; drains the two DMAs issued one half earlier.
    #pragma unroll 1
    for (int t = 0; t < NITER - 2; t += 2) {
        // tile t: QK(t+1) from KB1, PV(t) from VB0
        __syncthreads();                 // K(t+1)@KB1, V(t)@VB0 ready
        issueK(KB0, t + 2);
        issueV(VB1, t + 1);
        qk(KB1);
        pv(VB0);
        softmax2();                      // pfc = P(t+1)
        // tile t+1: QK(t+2) from KB0, PV(t+1) from VB1
        __syncthreads();                 // K(t+2)@KB0, V(t+1)@VB1 ready
        issueK(KB1, t + 3);              // t<=NITER-4 -> t+3 <= NITER-1, always valid
        issueV(VB0, t + 2);
        qk(KB0);
        pv(VB1);
        softmax2();                      // pfc = P(t+2)
    }

    // ---- epilogue: tiles NITER-2, NITER-1 (K(NITER-1)@KB1, V(NITER-2)@VB0 in flight) ----
    __syncthreads();
    issueV(VB1, NITER - 1);
    qk(KB1);                             // S(NITER-1)
    pv(VB0);                             // PV(NITER-2)
    softmax2();                          // pfc = P(NITER-1)
    __syncthreads();                     // V(NITER-1)@VB1 ready
    pv(VB1);                             // PV(NITER-1)

    // ---- finalize: l(q=m31) = lp(lane) + lp(lane^32); invert; scatter ----
    float lp = lp2.x + lp2.y;
    float v = lp;
    v += __shfl_xor(v, 32, 64);
    const float linv = 1.0f / v;

    #pragma unroll
    for (int dt = 0; dt < 2; ++dt) {
        const f32x16& o = dt ? o1 : o0;
        #pragma unroll
        for (int reg = 0; reg < 16; ++reg) {
            const int qp = (reg & 3) + 8 * (reg >> 2) + 4 * hl;
            const float rl = __shfl(linv, qp, 64);
            const int q = q0 + 32 * w + qp;
            Ob[(size_t)q * DH + 32 * dt + m31] = o[reg] * rl;
        }
    }
}

extern "C" void kernel_launch(void* const* d_in, const int* in_sizes, int n_in,
                              void* d_out, int out_size, void* d_ws, size_t ws_size,
                              hipStream_t stream) {
    const float* Q = (const float*)d_in[0];
    const float* K = (const float*)d_in[1];
    const float* V = (const float*)d_in[2];
    float* O = (float*)d_out;

    // workspace: bf16 K (12.6 MB) + bf16 V^T (12.6 MB)
    short* Kb  = (short*)d_ws;
    short* Vtg = Kb + (size_t)NBH * SQ * DH;

    prepass<<<dim3(KCONV_BLOCKS + NBH * 32), dim3(256), 0, stream>>>(K, Kb, V, Vtg);
    // 768 blocks, XCD-swizzled (head-locality in per-XCD L2); 32 KB LDS, 3 blocks/CU
    attn_fused_kernel<<<dim3(NBH * NQT), dim3(256), 0, stream>>>(Q, Kb, Vtg, O);
}

// Round 5
// 173.087 us; speedup vs baseline: 2.9907x; 1.0245x over previous
//
#include <hip/hip_runtime.h>

#define SQ 2048
#define DH 64
#define NH 12
#define NBH 48          // B*H
#define QTILE 128       // q rows per block (32 per wave)
#define KTILE 64        // keys per iteration
#define NITER (SQ / KTILE)
#define NQT (SQ / QTILE)   // 16 q-tiles -> 768 blocks = 3 blocks/CU

// LDS arena bases (literal)
#define KB0 0
#define KB1 8192
#define VB0 16384
#define VB1 24576

typedef short short8 __attribute__((ext_vector_type(8)));
typedef float f32x2  __attribute__((ext_vector_type(2)));
typedef float f32x4  __attribute__((ext_vector_type(4)));
typedef float f32x16 __attribute__((ext_vector_type(16)));
typedef int   i32x2 __attribute__((ext_vector_type(2)));
typedef int   i32x4 __attribute__((ext_vector_type(4)));

#define MFMA32(a, b, c) __builtin_amdgcn_mfma_f32_32x32x16_bf16(a, b, c, 0, 0, 0)

typedef __attribute__((address_space(1))) const void* gas_ptr;
typedef __attribute__((address_space(3))) void* las_ptr;

__device__ __forceinline__ void load_lds16(const void* g, void* l) {
    // 16B/lane direct global->LDS DMA; LDS dest = wave-uniform base + lane*16
    __builtin_amdgcn_global_load_lds((gas_ptr)g, (las_ptr)l, 16, 0, 0);
}

// two fp32 -> packed bf16x2 (low = a, high = b), RTNE
#if defined(__has_builtin) && __has_builtin(__builtin_amdgcn_cvt_pk_bf16_f32)
typedef __bf16 bf16x2_t __attribute__((ext_vector_type(2)));
__device__ __forceinline__ unsigned pk2bf(float a, float b) {
    bf16x2_t v = __builtin_amdgcn_cvt_pk_bf16_f32(a, b);
    union { bf16x2_t v; unsigned u; } c; c.v = v; return c.u;
}
#else
__device__ __forceinline__ unsigned pk2bf(float a, float b) {
    union { float f; unsigned u; } x, y; x.f = a; y.f = b;
    unsigned ra = x.u + 0x7FFFu + ((x.u >> 16) & 1u);
    unsigned rb = y.u + 0x7FFFu + ((y.u >> 16) & 1u);
    return (ra >> 16) | (rb & 0xFFFF0000u);
}
#endif

#ifdef __has_builtin
#if __has_builtin(__builtin_amdgcn_permlane32_swap)
#define HAVE_PLSWAP 1
#else
#define HAVE_PLSWAP 0
#endif
#else
#define HAVE_PLSWAP 0
#endif

// ------- fused pre-pass: K fp32->bf16 (blocks 0..3071)  |  V transpose (rest) -------
#define KCONV_BLOCKS (NBH * SQ * DH / 8 / 256)   // 3072
__global__ __launch_bounds__(256)
void prepass(const float* __restrict__ K, short* __restrict__ Kb,
             const float* __restrict__ V, short* __restrict__ Vt) {
    __shared__ float Ls[64][68];   // transpose staging (+4 pad)
    if (blockIdx.x < KCONV_BLOCKS) {
        const size_t i = (size_t)(blockIdx.x * 256 + threadIdx.x) * 8;
        f32x4 a = *(const f32x4*)&K[i];
        f32x4 b = *(const f32x4*)&K[i + 4];
        unsigned o[4] = { pk2bf(a[0], a[1]), pk2bf(a[2], a[3]),
                          pk2bf(b[0], b[1]), pk2bf(b[2], b[3]) };
        *(i32x4*)&Kb[i] = *(i32x4*)o;
        return;
    }
    const int bx = blockIdx.x - KCONV_BLOCKS;
    const int st = bx & 31;       // s tile
    const int bh = bx >> 5;
    const int b = bh / NH, h = bh % NH;
    const int s0 = st * 64;
    const float* src = V + ((size_t)b * SQ * NH + (size_t)h) * DH;
    const int dg = threadIdx.x & 15;   // d = 4*dg
    const int sl = threadIdx.x >> 4;   // 0..15
    #pragma unroll
    for (int p = 0; p < 4; ++p) {
        const int row = p * 16 + sl;
        *(f32x4*)&Ls[row][dg * 4] =
            *(const f32x4*)&src[(size_t)(s0 + row) * (NH * DH) + dg * 4];
    }
    __syncthreads();
    const int dr = threadIdx.x >> 2;        // d row 0..63
    const int sc = (threadIdx.x & 3) * 16;  // s chunk
    unsigned out[8];
    #pragma unroll
    for (int jj = 0; jj < 8; ++jj)
        out[jj] = pk2bf(Ls[sc + 2 * jj][dr], Ls[sc + 2 * jj + 1][dr]);
    short* dst = Vt + (size_t)bh * DH * SQ + (size_t)dr * SQ + s0 + sc;
    *(i32x4*)(dst)     = *(i32x4*)&out[0];
    *(i32x4*)(dst + 8) = *(i32x4*)&out[4];
}

// ---------------- main fused attention (32x32x16 MFMA, P-carry pipeline) ----------------
// Register-minimized tile order: {sync; DMA K(t+2),V(t+1); PV(t) [pfc_old dies];
// QK_a0(t+1); QK_a1(t+1); sm(a0)->pfc[0:2] [a1 in flight covers a0 latency];
// sm(a1)->pfc[2:4]}. Peak live ~= o(32)+qf(16)+a0(16)+a1(16)+misc ~= 100 regs
// (combined VGPR+AGPR, unified file). r4 carried pfc_old+sn across pv -> ~140 combined
// -> >128 -> HW capped at 2 waves/SIMD (Occupancy 24.5% = 8 waves/CU, 2 of 3 blocks
// resident). __launch_bounds__(256,4) enforces the <=128 budget -> all 3 blocks resident.
__global__ __launch_bounds__(256, 4)
void attn_fused_kernel(const float* __restrict__ Q,
                       const short* __restrict__ Kb,   // bf16 [BH][S][D]
                       const short* __restrict__ Vtg,  // bf16 [BH][D][S]
                       float* __restrict__ O) {
    // Kbuf j at KB(j&1) (halves +0 rows0-31, +4096 rows32-63)
    // Vbuf j at VB(j&1) (halves +0 d0-31,    +4096 d32-63)
    // XOR chunk swizzle (chunk c of row r at c^(r&7)); unpadded 128B rows.
    __shared__ __align__(16) char L[32768];

    const int tid  = threadIdx.x;
    const int lane = tid & 63;
    const int w    = tid >> 6;
    const int m31  = lane & 31;     // MFMA row/col index
    const int hl   = lane >> 5;     // half-wave 0/1
    const int l7   = lane & 7;

    // ---- XCD-locality swizzle: dispatch round-robins XCDs by (bx & 7).
    const int bx  = blockIdx.x;
    const int xcd = bx & 7;
    const int i96 = bx >> 3;          // 0..95
    const int bh  = xcd * 6 + (i96 % 6);
    const int qt  = i96 / 6;          // 0..15
    const int q0 = qt * QTILE;

    const float* Qb  = Q   + (size_t)bh * SQ * DH;
    const short* Kbh = Kb  + (size_t)bh * SQ * DH;
    const short* Vbh = Vtg + (size_t)bh * DH * SQ;
    float*       Ob  = O   + (size_t)bh * SQ * DH;

    // scale folded into Q, exp as exp2: 1/sqrt(768) * log2(e)
    const float qscale = 0.03608439182435161f * 1.4426950408889634f;

    // ---- Q fragments (B operand: n=m31 -> q row, k=16*s+8*hl+j) ----
    short8 qf[4];
    {
        const int qrow = q0 + 32 * w + m31;
        #pragma unroll
        for (int s = 0; s < 4; ++s) {
            const float* src = Qb + (size_t)qrow * DH + 16 * s + 8 * hl;
            f32x4 qa = *(const f32x4*)src;
            f32x4 qb = *(const f32x4*)(src + 4);
            union { unsigned u[4]; short8 v; } f;
            f.u[0] = pk2bf(qa[0] * qscale, qa[1] * qscale);
            f.u[1] = pk2bf(qa[2] * qscale, qa[3] * qscale);
            f.u[2] = pk2bf(qb[0] * qscale, qb[1] * qscale);
            f.u[3] = pk2bf(qb[2] * qscale, qb[3] * qscale);
            qf[s] = f.v;
        }
    }

    // ---- staging source pointers (lane-constant swizzle) ----
    const int gk = (lane & 7) ^ (lane >> 3);
    const int rr = w * 8 + (lane >> 3);
    const short* kg0 = Kbh + (size_t)rr * DH + gk * 8;
    const short* kg1 = kg0 + 32 * DH;
    const short* vg0 = Vbh + (size_t)rr * SQ + gk * 8;
    const short* vg1 = vg0 + 32 * SQ;
    const int wslot = w * 1024;   // scalar

    // ---- loop-invariant per-lane LDS frag addresses (bytes) ----
    int aoff[4];
    #pragma unroll
    for (int s = 0; s < 4; ++s) aoff[s] = m31 * 128 + (((2 * s + hl) ^ l7) * 16);

    // ---- pipeline state: captured named vars / constant-indexed arrays only ----
    f32x16 o0 = {}, o1 = {};     // output accumulators
    f32x16 sn0, sn1;             // current tile's score halves (die at their sm)
    short8 pfc[4];               // carried packed P fragments
    f32x2 lpa = {0.f, 0.f};      // row-sum accumulators (2 independent chains)
    f32x2 lpb = {0.f, 0.f};

    // issue K tile t into Kbuf base kb (2 KB/wave via DMA)
    auto issueK = [&](int kb, int t) {
        const short* p0 = kg0 + (size_t)t * (KTILE * DH);
        const short* p1 = kg1 + (size_t)t * (KTILE * DH);
        load_lds16(p0, L + kb + wslot);
        load_lds16(p1, L + kb + 4096 + wslot);
    };
    // issue V tile t into Vbuf base vb
    auto issueV = [&](int vb, int t) {
        const short* p0 = vg0 + (size_t)t * KTILE;
        const short* p1 = vg1 + (size_t)t * KTILE;
        load_lds16(p0, L + vb + wslot);
        load_lds16(p1, L + vb + 4096 + wslot);
    };

    // QK^T halves from Kbuf base kb -> sn0 / sn1
    auto qk_h0 = [&](int kb) {
        f32x16 a = {};
        #pragma unroll
        for (int s = 0; s < 4; ++s)
            a = MFMA32(*(const short8*)(L + kb + aoff[s]), qf[s], a);
        sn0 = a;
    };
    auto qk_h1 = [&](int kb) {
        f32x16 a = {};
        #pragma unroll
        for (int s = 0; s < 4; ++s)
            a = MFMA32(*(const short8*)(L + kb + 4096 + aoff[s]), qf[s], a);
        sn1 = a;
    };

    // exp + in-register C->A relayout; consumes one score half into dst[0..1]
    auto softmax_pack = [&](const f32x16& sv, short8* dst) {
        #pragma unroll
        for (int wd = 0; wd < 2; ++wd) {
            float p[8];
            #pragma unroll
            for (int j = 0; j < 8; ++j)
                p[j] = __builtin_amdgcn_exp2f(sv[8 * wd + j]);
            // row-sum via packed v_pk_add_f32, two independent accumulator chains
            f32x2 s01 = {p[0], p[1]}, s23 = {p[2], p[3]};
            f32x2 s45 = {p[4], p[5]}, s67 = {p[6], p[7]};
            lpa += (s01 + s23);
            lpb += (s45 + s67);
            unsigned a0 = pk2bf(p[0], p[1]);   // kk 4hl+{0,1}
            unsigned a1 = pk2bf(p[2], p[3]);   // kk 4hl+{2,3}
            unsigned b0 = pk2bf(p[4], p[5]);   // kk 8+4hl+{0,1}
            unsigned b1 = pk2bf(p[6], p[7]);   // kk 8+4hl+{2,3}
            union { unsigned u[4]; short8 v; } fr;
#if HAVE_PLSWAP
            // r.x = {lo: a[0:31]  | hi: b[0:31]}  = A-frag word0
            // r.y = {lo: a[32:63] | hi: b[32:63]} = A-frag word2
            i32x2 r0 = __builtin_amdgcn_permlane32_swap((int)a0, (int)b0, false, false);
            i32x2 r1 = __builtin_amdgcn_permlane32_swap((int)a1, (int)b1, false, false);
            fr.u[0] = (unsigned)r0.x;
            fr.u[1] = (unsigned)r1.x;
            fr.u[2] = (unsigned)r0.y;
            fr.u[3] = (unsigned)r1.y;
#else
            unsigned r0 = (unsigned)__shfl_xor((int)(hl ? a0 : b0), 32, 64);
            unsigned r1 = (unsigned)__shfl_xor((int)(hl ? a1 : b1), 32, 64);
            fr.u[0] = hl ? r0 : a0;
            fr.u[1] = hl ? r1 : a1;
            fr.u[2] = hl ? b0 : r0;
            fr.u[3] = hl ? b1 : r1;
#endif
            dst[wd] = fr.v;
        }
    };

    // PV accumulate from Vbuf base vb with carried pfc (pfc dies here)
    auto pv = [&](int vb) {
        #pragma unroll
        for (int s = 0; s < 4; ++s) {
            short8 vv0 = *(const short8*)(L + vb + aoff[s]);
            short8 vv1 = *(const short8*)(L + vb + 4096 + aoff[s]);
            o0 = MFMA32(pfc[s], vv0, o0);
            o1 = MFMA32(pfc[s], vv1, o1);
        }
    };

    // one pipelined tile step: PV(t) from vb_rd, QK(t+1) from kb_rd, sm -> pfc
    auto tile_step = [&](int kb_rd, int vb_rd) {
        __builtin_amdgcn_s_setprio(1);
        pv(vb_rd);        // PV(t): pfc_old consumed, registers freed
        qk_h0(kb_rd);     // a0(t+1)
        qk_h1(kb_rd);     // a1(t+1), covers a0's latency for sm below
        __builtin_amdgcn_s_setprio(0);
        softmax_pack(sn0, &pfc[0]);
        softmax_pack(sn1, &pfc[2]);
    };

    // ---- prologue: K0,V0,K1 in flight; pfc = P(0) ----
    issueK(KB0, 0); issueV(VB0, 0); issueK(KB1, 1);
    __syncthreads();
    qk_h0(KB0); qk_h1(KB0);
    softmax_pack(sn0, &pfc[0]);
    softmax_pack(sn1, &pfc[2]);

    // ---- pipelined main loop, manually unrolled x2 (tiles t..t+1), literal bases ----
    // Barrier at top of each half: all waves finished the previous half's QK/PV, so the
    // buffer being overwritten is dead; drains the two DMAs issued one half earlier.
    #pragma unroll 1
    for (int t = 0; t < NITER - 2; t += 2) {
        // tile t: PV(t) from VB0, QK(t+1) from KB1
        __syncthreads();                 // K(t+1)@KB1, V(t)@VB0 ready
        issueK(KB0, t + 2);
        issueV(VB1, t + 1);
        tile_step(KB1, VB0);             // pfc = P(t+1)
        // tile t+1: PV(t+1) from VB1, QK(t+2) from KB0
        __syncthreads();                 // K(t+2)@KB0, V(t+1)@VB1 ready
        issueK(KB1, t + 3);              // t<=NITER-4 -> t+3 <= NITER-1, always valid
        issueV(VB0, t + 2);
        tile_step(KB0, VB1);             // pfc = P(t+2)
    }

    // ---- epilogue: tiles NITER-2, NITER-1 (K(NITER-1)@KB1, V(NITER-2)@VB0 in flight) ----
    __syncthreads();
    issueV(VB1, NITER - 1);
    tile_step(KB1, VB0);                 // PV(NITER-2), S(NITER-1) -> pfc = P(NITER-1)
    __syncthreads();                     // V(NITER-1)@VB1 ready
    pv(VB1);                             // PV(NITER-1)

    // ---- finalize: l(q=m31) = lp(lane) + lp(lane^32); invert; scatter ----
    float lp = (lpa.x + lpa.y) + (lpb.x + lpb.y);
    float v = lp;
    v += __shfl_xor(v, 32, 64);
    const float linv = 1.0f / v;

    #pragma unroll
    for (int dt = 0; dt < 2; ++dt) {
        const f32x16& o = dt ? o1 : o0;
        #pragma unroll
        for (int reg = 0; reg < 16; ++reg) {
            const int qp = (reg & 3) + 8 * (reg >> 2) + 4 * hl;
            const float rl = __shfl(linv, qp, 64);
            const int q = q0 + 32 * w + qp;
            Ob[(size_t)q * DH + 32 * dt + m31] = o[reg] * rl;
        }
    }
}

extern "C" void kernel_launch(void* const* d_in, const int* in_sizes, int n_in,
                              void* d_out, int out_size, void* d_ws, size_t ws_size,
                              hipStream_t stream) {
    const float* Q = (const float*)d_in[0];
    const float* K = (const float*)d_in[1];
    const float* V = (const float*)d_in[2];
    float* O = (float*)d_out;

    // workspace: bf16 K (12.6 MB) + bf16 V^T (12.6 MB)
    short* Kb  = (short*)d_ws;
    short* Vtg = Kb + (size_t)NBH * SQ * DH;

    prepass<<<dim3(KCONV_BLOCKS + NBH * 32), dim3(256), 0, stream>>>(K, Kb, V, Vtg);
    // 768 blocks, XCD-swizzled (head-locality in per-XCD L2); 32 KB LDS, 3 blocks/CU
    attn_fused_kernel<<<dim3(NBH * NQT), dim3(256), 0, stream>>>(Q, Kb, Vtg, O);
}